// Round 5
// baseline (500.330 us; speedup 1.0000x reference)
//
#include <hip/hip_runtime.h>
#include <cstdint>
#include <cstddef>

typedef __attribute__((ext_vector_type(8))) short frag8;
typedef __attribute__((ext_vector_type(4))) float f32x4;

static __device__ __forceinline__ unsigned short f2bf_r(float f) {
    return (unsigned short)((__float_as_uint(f) + 0x8000u) >> 16);   // round-half-up
}

// async global->LDS, 16B per lane. LDS dest = wave-uniform base + lane*16.
static __device__ __forceinline__ void gll16(const void* g, void* l) {
    __builtin_amdgcn_global_load_lds(
        (const __attribute__((address_space(1))) unsigned int*)g,
        (__attribute__((address_space(3))) unsigned int*)l, 16, 0, 0);
}

// ---------------- fused MLP: out = relu(X@W1+b1)@W2' + b2' ----------------------
// X fp32 [65536][512]; W1T bf16 [256][512]; W2T bf16 [256][256]; out bf16 [65536][256].
// B-fragments loaded DIRECTLY global->VGPR (weights are L2-resident) -> no gll,
// no vmcnt drain at barriers, LDS = 43KB -> 3 blocks/CU.
__global__ __launch_bounds__(256, 3)
void mlp_fused(const float* __restrict__ X0, const float* __restrict__ X1,
               const unsigned short* __restrict__ W1T0, const unsigned short* __restrict__ W1T1,
               const float* __restrict__ b1v0, const float* __restrict__ b1v1,
               const unsigned short* __restrict__ W2T0, const unsigned short* __restrict__ W2T1,
               const float* __restrict__ b2v0, const float* __restrict__ b2v1,
               unsigned short* __restrict__ O0, unsigned short* __restrict__ O1)
{
    __shared__ __align__(16) unsigned short As[64 * 72];     // 9216 B
    __shared__ __align__(16) unsigned short hs[64 * 264];    // 33792 B (h tile / C-stage)

    const int mod = blockIdx.y;
    const float* X = mod ? X1 : X0;
    const unsigned short* W1T = mod ? W1T1 : W1T0;
    const unsigned short* W2T = mod ? W2T1 : W2T0;
    const float* b1 = mod ? b1v1 : b1v0;
    const float* b2 = mod ? b2v1 : b2v0;
    unsigned short* O = mod ? O1 : O0;

    const int t    = threadIdx.x;
    const int wave = t >> 6;
    const int lane = t & 63;
    const int quad = lane >> 4;
    const int l15  = lane & 15;
    const int wn   = wave * 64;
    const int m0   = blockIdx.x * 64;

    // per-thread X staging coords: 4 chunks of (row, 4 cols)
    int xrow[4], xcol[4];
    #pragma unroll
    for (int p = 0; p < 4; ++p) {
        const int idx = p * 256 + t;
        xrow[p] = idx >> 4;
        xcol[p] = (idx & 15) * 4;
    }

    f32x4 acc[4][4];
    #pragma unroll
    for (int i = 0; i < 4; ++i)
        #pragma unroll
        for (int j = 0; j < 4; ++j)
            acc[i][j] = (f32x4){0.f, 0.f, 0.f, 0.f};

    // prefetch X for k0 = 0
    float4 xv[4];
    #pragma unroll
    for (int p = 0; p < 4; ++p)
        xv[p] = *(const float4*)(X + (size_t)(m0 + xrow[p]) * 512 + xcol[p]);

    // ---------------- phase 1: h = relu(X@W1+b1), K=512, BK=64 ----------------
    for (int k0 = 0; k0 < 512; k0 += 64) {
        // B frags: direct global (L2-hot weights)
        frag8 bf[2][4];
        #pragma unroll
        for (int kh = 0; kh < 2; ++kh)
            #pragma unroll
            for (int j = 0; j < 4; ++j)
                bf[kh][j] = *(const frag8*)(W1T + (size_t)(wn + j * 16 + l15) * 512 + k0 + kh * 32 + quad * 8);
        // stage current X chunk (fp32 -> bf16) into As
        #pragma unroll
        for (int p = 0; p < 4; ++p) {
            const unsigned int a0 = __float_as_uint(xv[p].x) + 0x8000u;
            const unsigned int a1 = __float_as_uint(xv[p].y) + 0x8000u;
            const unsigned int a2 = __float_as_uint(xv[p].z) + 0x8000u;
            const unsigned int a3 = __float_as_uint(xv[p].w) + 0x8000u;
            uint2 pk;
            pk.x = __builtin_amdgcn_perm(a1, a0, 0x07060302u);
            pk.y = __builtin_amdgcn_perm(a3, a2, 0x07060302u);
            *(uint2*)&As[xrow[p] * 72 + xcol[p]] = pk;
        }
        // prefetch next X chunk
        if (k0 < 448) {
            #pragma unroll
            for (int p = 0; p < 4; ++p)
                xv[p] = *(const float4*)(X + (size_t)(m0 + xrow[p]) * 512 + (k0 + 64) + xcol[p]);
        }
        __syncthreads();                       // lgkm-only drain (ds_write)

        frag8 af[2][4];
        #pragma unroll
        for (int i = 0; i < 4; ++i)
            #pragma unroll
            for (int kh = 0; kh < 2; ++kh)
                af[kh][i] = *(const frag8*)&As[(i * 16 + l15) * 72 + kh * 32 + quad * 8];
        #pragma unroll
        for (int kh = 0; kh < 2; ++kh)
            #pragma unroll
            for (int i = 0; i < 4; ++i)
                #pragma unroll
                for (int j = 0; j < 4; ++j)
                    acc[i][j] = __builtin_amdgcn_mfma_f32_16x16x32_bf16(af[kh][i], bf[kh][j], acc[i][j], 0, 0, 0);
        __syncthreads();
    }

    // h -> LDS (bias + relu + bf16)
    #pragma unroll
    for (int j = 0; j < 4; ++j) {
        const int col = wn + j * 16 + l15;
        const float bv = b1[col];
        #pragma unroll
        for (int i = 0; i < 4; ++i) {
            const int rl = i * 16 + quad * 4;
            #pragma unroll
            for (int r = 0; r < 4; ++r)
                hs[(rl + r) * 264 + col] = f2bf_r(fmaxf(acc[i][j][r] + bv, 0.0f));
        }
    }
    __syncthreads();

    // ---------------- phase 2: out = h@W2' + b2', K=256 — ZERO barriers -------
    #pragma unroll
    for (int i = 0; i < 4; ++i)
        #pragma unroll
        for (int j = 0; j < 4; ++j)
            acc[i][j] = (f32x4){0.f, 0.f, 0.f, 0.f};

    #pragma unroll
    for (int k0 = 0; k0 < 256; k0 += 64) {
        frag8 bf[2][4], af[2][4];
        #pragma unroll
        for (int kh = 0; kh < 2; ++kh)
            #pragma unroll
            for (int j = 0; j < 4; ++j)
                bf[kh][j] = *(const frag8*)(W2T + (size_t)(wn + j * 16 + l15) * 256 + k0 + kh * 32 + quad * 8);
        #pragma unroll
        for (int i = 0; i < 4; ++i)
            #pragma unroll
            for (int kh = 0; kh < 2; ++kh)
                af[kh][i] = *(const frag8*)&hs[(i * 16 + l15) * 264 + k0 + kh * 32 + quad * 8];
        #pragma unroll
        for (int kh = 0; kh < 2; ++kh)
            #pragma unroll
            for (int i = 0; i < 4; ++i)
                #pragma unroll
                for (int j = 0; j < 4; ++j)
                    acc[i][j] = __builtin_amdgcn_mfma_f32_16x16x32_bf16(af[kh][i], bf[kh][j], acc[i][j], 0, 0, 0);
    }
    __syncthreads();                           // all hs reads done before reuse

    // epilogue: bias -> bf16 -> hs C-stage -> coalesced 16B stores
    #pragma unroll
    for (int j = 0; j < 4; ++j) {
        const int col = wn + j * 16 + l15;
        const float bv = b2[col];
        #pragma unroll
        for (int i = 0; i < 4; ++i) {
            const int rl = i * 16 + quad * 4;
            #pragma unroll
            for (int r = 0; r < 4; ++r)
                hs[(rl + r) * 264 + col] = f2bf_r(acc[i][j][r] + bv);
        }
    }
    __syncthreads();
    #pragma unroll
    for (int u = 0; u < 8; ++u) {
        const int chunk = u * 256 + t;
        const int row = chunk >> 5;
        const int c16 = (chunk & 31) * 8;
        uint4 v = *(const uint4*)&hs[row * 264 + c16];
        *(uint4*)&O[(size_t)(m0 + row) * 256 + c16] = v;
    }
}

// ---------------- lag correlation GEMM, balanced 512-block grid, BK=128 -----------
// Flat work per tile: 9 deltas x 512 K-steps = 4608 steps; 32 chunks of 144.
// Chunk crossing a delta boundary flushes per-segment into slice (2c+seg).
__global__ __launch_bounds__(256, 2)
void gemm_corr(const unsigned short* __restrict__ A, const unsigned short* __restrict__ B,
               float* __restrict__ partial)
{
    __shared__ __align__(16) unsigned short As[128 * 128];   // 32 KB
    __shared__ __align__(16) unsigned short Bs[128 * 128];   // 32 KB

    const int t    = threadIdx.x;
    const int wave = t >> 6;
    const int lane = t & 63;
    const int quad = lane >> 4;
    const int l15  = lane & 15;
    const int wm   = (wave >> 1) * 64;
    const int wn   = (wave & 1) * 64;
    const int tile = blockIdx.y;
    const int m0   = (tile >> 2) * 128;
    const int n0   = (tile & 3) * 128;
    const int c    = blockIdx.x;               // chunk 0..31

    // gll mapping: call p stages rows [wave*32+p*4, +4) x 128 cols; lane: row rloc, granule g
    const int rloc = lane >> 4;                // 0..3
    const int g    = lane & 15;
    const unsigned short* Abase = A + (size_t)m0 * 32768;
    const unsigned short* Bbase = B + (size_t)n0 * 32768;

    f32x4 acc[4][4];
    #pragma unroll
    for (int i = 0; i < 4; ++i)
        #pragma unroll
        for (int j = 0; j < 4; ++j)
            acc[i][j] = (f32x4){0.f, 0.f, 0.f, 0.f};

    int seg = 0;
    int s = c * 144;
    const int s1 = s + 144;
    while (s < s1) {
        const int d    = s >> 9;                       // delta index 0..8
        const int send = min(s1, (d + 1) << 9);
        const int koff = (32768 - 256 * (d - 4)) & 32767;
        for (; s < send; s += 2) {                     // BK = 128 (two 64-steps)
            const int kA = (s & 511) << 6;             // multiple of 128
            const int kB = (kA + koff) & 32767;        // multiple of 128, no intra-row wrap
            #pragma unroll
            for (int p = 0; p < 8; ++p) {
                const int rlo = p * 4 + rloc;          // 0..31 within wave's rows
                const int sc  = ((g ^ (rlo & 15)) << 3);
                const int row = wave * 32 + rlo;
                gll16(Abase + (size_t)row * 32768 + kA + sc, &As[(wave * 32 + p * 4) * 128]);
                gll16(Bbase + (size_t)row * 32768 + kB + sc, &Bs[(wave * 32 + p * 4) * 128]);
            }
            __syncthreads();

            #pragma unroll
            for (int kh = 0; kh < 4; ++kh) {
                frag8 af[4], bf[4];
                #pragma unroll
                for (int i = 0; i < 4; ++i) {
                    const int q = (kh * 4 + quad) ^ l15;
                    af[i] = *(const frag8*)&As[(wm + i * 16 + l15) * 128 + (q << 3)];
                }
                #pragma unroll
                for (int j = 0; j < 4; ++j) {
                    const int q = (kh * 4 + quad) ^ l15;
                    bf[j] = *(const frag8*)&Bs[(wn + j * 16 + l15) * 128 + (q << 3)];
                }
                #pragma unroll
                for (int i = 0; i < 4; ++i)
                    #pragma unroll
                    for (int j = 0; j < 4; ++j)
                        acc[i][j] = __builtin_amdgcn_mfma_f32_16x16x32_bf16(af[i], bf[j], acc[i][j], 0, 0, 0);
            }
            __syncthreads();
        }
        // flush this segment to slice (2c + seg)
        float* C = partial + (size_t)(2 * c + seg) * 262144;
        #pragma unroll
        for (int i = 0; i < 4; ++i) {
            const int rg = m0 + wm + i * 16 + quad * 4;
            #pragma unroll
            for (int j = 0; j < 4; ++j) {
                const int cg = n0 + wn + j * 16 + l15;
                #pragma unroll
                for (int r = 0; r < 4; ++r)
                    C[(size_t)(rg + r) * 512 + cg] = acc[i][j][r];
            }
        }
        ++seg;
        if (s < s1) {
            #pragma unroll
            for (int i = 0; i < 4; ++i)
                #pragma unroll
                for (int j = 0; j < 4; ++j)
                    acc[i][j] = (f32x4){0.f, 0.f, 0.f, 0.f};
        }
    }
}

// ---------------- prep: weight transposes + Wc fold in one dispatch ---------------
__global__ void prep(const float* __restrict__ a_w1, const float* __restrict__ v_w1,
                     const float* __restrict__ a_w2, const float* __restrict__ v_w2,
                     const float* __restrict__ W, const float* __restrict__ v_b2,
                     unsigned short* __restrict__ aw1T, unsigned short* __restrict__ vw1T,
                     unsigned short* __restrict__ aw2T,
                     unsigned short* __restrict__ WcT, float* __restrict__ bc)
{
    const int b = blockIdx.x;
    __shared__ float tl[32][33];
    __shared__ float wcol[256];
    if (b < 320) {
        const float* src; unsigned short* dst; int R, C, tile;
        if (b < 128)      { src = a_w1; dst = aw1T; R = 512; C = 256; tile = b; }
        else if (b < 256) { src = v_w1; dst = vw1T; R = 512; C = 256; tile = b - 128; }
        else              { src = a_w2; dst = aw2T; R = 256; C = 256; tile = b - 256; }
        const int tilesX = C / 32;
        const int bx = (tile % tilesX) * 32, by = (tile / tilesX) * 32;
        const int tx = threadIdx.x & 31, ty = threadIdx.x >> 5;
        #pragma unroll
        for (int r = ty; r < 32; r += 8)
            tl[r][tx] = src[(size_t)(by + r) * C + bx + tx];
        __syncthreads();
        #pragma unroll
        for (int c = ty; c < 32; c += 8)
            dst[(size_t)(bx + c) * R + by + tx] = f2bf_r(tl[tx][c]);
    } else {
        const int n = b - 320, k = threadIdx.x;
        wcol[k] = W[(size_t)k * 256 + n];
        __syncthreads();
        float s = 0.f;
        #pragma unroll 8
        for (int d = 0; d < 256; ++d) s += v_w2[(size_t)k * 256 + d] * wcol[d];
        WcT[(size_t)n * 256 + k] = f2bf_r(s);
        if (k == 0) {
            float tt = 0.f;
            for (int d = 0; d < 256; ++d) tt += v_b2[d] * wcol[d];
            bc[n] = tt;
        }
    }
}

// out[q,c] = max_d sum over slices mapped to delta d (static chunk->delta map)
__global__ void reduce_lag(const float* __restrict__ partial, float* __restrict__ out) {
    const int idx = blockIdx.x * blockDim.x + threadIdx.x;
    float best = -3.4e38f;
    #pragma unroll
    for (int d = 0; d < 9; ++d) {
        float s = 0.f;
        const int sb = d << 9, se = sb + 512;
        #pragma unroll 5
        for (int c = sb / 144; c * 144 < se; ++c) {
            const int d0 = (c * 144) >> 9;
            const int seg = (d0 == d) ? 0 : 1;
            s += partial[(size_t)(2 * c + seg) * 262144 + idx];
        }
        best = fmaxf(best, s);
    }
    out[idx] = best;
}

extern "C" void kernel_launch(void* const* d_in, const int* in_sizes, int n_in,
                              void* d_out, int out_size, void* d_ws, size_t ws_size,
                              hipStream_t stream) {
    const float* audio = (const float*)d_in[0];
    const float* video = (const float*)d_in[1];
    const float* a_w1  = (const float*)d_in[2];
    const float* a_b1  = (const float*)d_in[3];
    const float* a_w2  = (const float*)d_in[4];
    const float* a_b2  = (const float*)d_in[5];
    const float* v_w1  = (const float*)d_in[6];
    const float* v_b1  = (const float*)d_in[7];
    const float* v_w2  = (const float*)d_in[8];
    const float* v_b2  = (const float*)d_in[9];
    const float* Wm    = (const float*)d_in[10];

    char* ws = (char*)d_ws;
    unsigned short* aw1T = (unsigned short*)(ws + 0);          // [256][512]
    unsigned short* vw1T = (unsigned short*)(ws + 262144);     // [256][512]
    unsigned short* aw2T = (unsigned short*)(ws + 524288);     // [256][256]
    unsigned short* WcT  = (unsigned short*)(ws + 655360);     // [256][256]
    float*          bc   = (float*)(ws + 786432);              // [256]
    unsigned short* a_bf = (unsigned short*)(ws + 1048576);    // [512][32768] bf16
    unsigned short* pv   = (unsigned short*)(ws + 34603008);   // [512][32768] bf16
    float* partial       = (float*)(ws + 68157440);            // [64][512][512] fp32 (67.1 MB)
    float* out = (float*)d_out;

    // 1: weight prep
    prep<<<dim3(576), 256, 0, stream>>>(a_w1, v_w1, a_w2, v_w2, Wm, v_b2,
                                        aw1T, vw1T, aw2T, WcT, bc);
    // 2: fused two-layer MLP, both modalities
    mlp_fused<<<dim3(1024, 2), 256, 0, stream>>>(
        audio, video, aw1T, vw1T, a_b1, v_b1, aw2T, WcT, a_b2, bc, a_bf, pv);
    // 3: lag correlation, balanced 512-block grid
    gemm_corr<<<dim3(32, 16), 256, 0, stream>>>(a_bf, pv, partial);
    // 4: per-delta segment sum + max
    reduce_lag<<<dim3(1024), 256, 0, stream>>>(partial, out);
}